// Round 1
// baseline (1942.767 us; speedup 1.0000x reference)
//
#include <hip/hip_runtime.h>

#define B_ROWS 8192
#define DDIM 1024
#define HDIM 4096
#define H2DIM 2048
#define DOUT_N 1024
#define NEXP 8
#define ROW_TILES 264            // ceil((2*8192 + 8*63)/64) = 264 tiles worst case
#define PAD_ROWS (ROW_TILES*64)  // 16896

typedef __attribute__((ext_vector_type(8))) short short8;
typedef __attribute__((ext_vector_type(4))) float f32x4;

// RNE fp32 -> bf16 (finite inputs only)
__device__ inline unsigned short f2bf(float f) {
  unsigned int u = __builtin_bit_cast(unsigned int, f);
  u += 0x7fffu + ((u >> 16) & 1u);
  return (unsigned short)(u >> 16);
}

// ---------------- gate layer 1: g = relu(x @ Wg1 + bg1), fp32 ----------------
// [8192,1024] @ [1024,512]; 64x64 tile, 256 thr, 4x4/thread, K-step 16
__global__ __launch_bounds__(256) void gate1_kernel(
    const float* __restrict__ x, const float* __restrict__ Wg1,
    const float* __restrict__ bg1, float* __restrict__ g) {
  __shared__ float a_s[16][64];
  __shared__ float b_s[16][64];
  const int t = threadIdx.x;
  const int row0 = blockIdx.y * 64;
  const int n0 = blockIdx.x * 64;
  const int tx = t & 15, ty = t >> 4;
  float c[4][4] = {};
  const int arow = t & 63, akk0 = (t >> 6) * 4;
  const int bkk = t >> 4, bc0 = (t & 15) * 4;
  for (int k0 = 0; k0 < DDIM; k0 += 16) {
    float4 av = *(const float4*)&x[(size_t)(row0 + arow) * DDIM + k0 + akk0];
    a_s[akk0 + 0][arow] = av.x; a_s[akk0 + 1][arow] = av.y;
    a_s[akk0 + 2][arow] = av.z; a_s[akk0 + 3][arow] = av.w;
    *(float4*)&b_s[bkk][bc0] = *(const float4*)&Wg1[(size_t)(k0 + bkk) * 512 + n0 + bc0];
    __syncthreads();
#pragma unroll
    for (int kk = 0; kk < 16; ++kk) {
      float4 a4 = *(const float4*)&a_s[kk][ty * 4];
      float4 b4 = *(const float4*)&b_s[kk][tx * 4];
      float aa[4] = {a4.x, a4.y, a4.z, a4.w};
      float bb[4] = {b4.x, b4.y, b4.z, b4.w};
#pragma unroll
      for (int i = 0; i < 4; ++i)
#pragma unroll
        for (int j = 0; j < 4; ++j) c[i][j] += aa[i] * bb[j];
    }
    __syncthreads();
  }
#pragma unroll
  for (int i = 0; i < 4; ++i) {
    float4 v;
    v.x = fmaxf(c[i][0] + bg1[n0 + tx * 4 + 0], 0.f);
    v.y = fmaxf(c[i][1] + bg1[n0 + tx * 4 + 1], 0.f);
    v.z = fmaxf(c[i][2] + bg1[n0 + tx * 4 + 2], 0.f);
    v.w = fmaxf(c[i][3] + bg1[n0 + tx * 4 + 3], 0.f);
    *(float4*)&g[(size_t)(row0 + ty * 4 + i) * 512 + n0 + tx * 4] = v;
  }
}

// ------ gate layer 2 + softmax + top2 + renorm + usage/count accumulation ----
// one wave per row; fp32 exact path to keep routing identical to numpy ref
__global__ __launch_bounds__(256) void gate2_kernel(
    const float* __restrict__ g, const float* __restrict__ Wg2,
    const float* __restrict__ bg2, int* __restrict__ top_idx,
    float* __restrict__ top_w, int* __restrict__ counts,
    float* __restrict__ usage) {
  __shared__ float w2t[NEXP * 512];  // transposed [e][k]
  __shared__ float us[NEXP];
  __shared__ int cs[NEXP];
  const int t = threadIdx.x;
  for (int i = t; i < NEXP * 512; i += 256) {
    int k = i >> 3, e = i & 7;
    w2t[e * 512 + k] = Wg2[i];
  }
  if (t < NEXP) { us[t] = 0.f; cs[t] = 0; }
  __syncthreads();
  const int lane = t & 63, wid = t >> 6;
  const int row = blockIdx.x * 4 + wid;
  float part[NEXP] = {};
  const float* grow = &g[(size_t)row * 512];
#pragma unroll
  for (int j = 0; j < 8; ++j) {
    int k = lane + j * 64;
    float gv = grow[k];
#pragma unroll
    for (int e = 0; e < NEXP; ++e) part[e] += gv * w2t[e * 512 + k];
  }
#pragma unroll
  for (int e = 0; e < NEXP; ++e)
    for (int m = 32; m >= 1; m >>= 1) part[e] += __shfl_xor(part[e], m);
  if (lane == 0) {
    float p[NEXP];
    float mx = -1e30f;
#pragma unroll
    for (int e = 0; e < NEXP; ++e) { p[e] = part[e] + bg2[e]; mx = fmaxf(mx, p[e]); }
    float s = 0.f;
#pragma unroll
    for (int e = 0; e < NEXP; ++e) { p[e] = expf(p[e] - mx); s += p[e]; }
    float inv = 1.f / s;
#pragma unroll
    for (int e = 0; e < NEXP; ++e) { p[e] *= inv; atomicAdd(&us[e], p[e]); }
    int i0 = 0; float b0 = p[0];
    for (int e = 1; e < NEXP; ++e) if (p[e] > b0) { b0 = p[e]; i0 = e; }
    int i1 = -1; float b1 = -1.f;
    for (int e = 0; e < NEXP; ++e) {
      if (e == i0) continue;
      if (p[e] > b1) { b1 = p[e]; i1 = e; }
    }
    float e1 = expf(b1 - b0);          // renorm = softmax over the 2 top probs
    float w0 = 1.f / (1.f + e1);
    top_idx[row * 2 + 0] = i0; top_idx[row * 2 + 1] = i1;
    top_w[row * 2 + 0] = w0;   top_w[row * 2 + 1] = e1 * w0;
    atomicAdd(&cs[i0], 1); atomicAdd(&cs[i1], 1);
  }
  __syncthreads();
  if (t < NEXP) { atomicAdd(&usage[t], us[t]); atomicAdd(&counts[t], cs[t]); }
}

// --------- offsets: 64-aligned segment starts per expert (single thread) -----
__global__ void offsets_kernel(const int* __restrict__ counts, int* __restrict__ off) {
  if (threadIdx.x == 0) {
    int acc = 0;
    off[0] = 0;
    for (int e = 0; e < NEXP; ++e) {
      acc += (counts[e] + 63) & ~63;
      off[e + 1] = acc;
    }
  }
}

// --------- scatter rows into per-expert entry lists (entry = row*2+k) --------
__global__ __launch_bounds__(256) void scatter_kernel(
    const int* __restrict__ top_idx, const int* __restrict__ off,
    int* __restrict__ fill, int* __restrict__ entry) {
  int row = blockIdx.x * 256 + threadIdx.x;
#pragma unroll
  for (int k = 0; k < 2; ++k) {
    int e = top_idx[row * 2 + k];
    int pos = atomicAdd(&fill[e], 1);
    entry[off[e] + pos] = row * 2 + k;
  }
}

// --------- gather x rows (fp32) -> dense bf16 A matrix by entry position -----
__global__ __launch_bounds__(256) void gather_kernel(
    const float* __restrict__ x, const int* __restrict__ entry,
    unsigned short* __restrict__ Xg) {
  const int r = blockIdx.x;
  const int s = entry[r];
  const int t = threadIdx.x;
  unsigned long long packed = 0ull;
  if (s >= 0) {
    float4 f = *(const float4*)&x[(size_t)(s >> 1) * DDIM + t * 4];
    packed = (unsigned long long)f2bf(f.x) |
             ((unsigned long long)f2bf(f.y) << 16) |
             ((unsigned long long)f2bf(f.z) << 32) |
             ((unsigned long long)f2bf(f.w) << 48);
  }
  *(unsigned long long*)&Xg[(size_t)r * DDIM + t * 4] = packed;
}

// --------- weight transpose+convert: [K][N] fp32 -> [N][K] bf16 per expert ---
__global__ __launch_bounds__(256) void transpose_kernel(
    const float* __restrict__ src, unsigned short* __restrict__ dst,
    int K, int N) {
  __shared__ float tile[64][65];
  const size_t eoff = (size_t)blockIdx.z * K * N;
  const int k0 = blockIdx.y * 64, n0 = blockIdx.x * 64;
  const int t = threadIdx.x;
#pragma unroll
  for (int i = 0; i < 16; ++i) {
    int idx = t + i * 256;
    int kk = idx >> 6, nn = idx & 63;
    tile[kk][nn] = src[eoff + (size_t)(k0 + kk) * N + n0 + nn];
  }
  __syncthreads();
#pragma unroll
  for (int i = 0; i < 16; ++i) {
    int idx = t + i * 256;
    int nn = idx >> 6, kk = idx & 63;
    dst[eoff + (size_t)(n0 + nn) * K + k0 + kk] = f2bf(tile[kk][nn]);
  }
}

// ---------------- expert GEMM: C[64 rows][64 cols] per block -----------------
// A: [PAD_ROWS][KDIM] bf16 dense by entry pos; Bt: [E][N][KDIM] bf16
// EPI 0: relu(acc+bias) -> bf16 Cout ; EPI 1: atomicAdd(out, w*(acc+bias))
template <int KDIM, int EPI>
__global__ __launch_bounds__(256) void expert_gemm(
    const unsigned short* __restrict__ A, const unsigned short* __restrict__ Bt,
    const float* __restrict__ bias, unsigned short* __restrict__ Cout,
    float* __restrict__ dOut, const float* __restrict__ topw,
    const int* __restrict__ entry, const int* __restrict__ off, int N) {
  const int tileM = blockIdx.y * 64;
  if (tileM >= off[NEXP]) return;  // beyond padded total: uniform exit
  int e = 0;
  while (e < NEXP - 1 && off[e + 1] <= tileM) ++e;
  const int tileN = blockIdx.x * 64;
  // stride 40 elems = 80B rows: 16B-aligned b128, worst 2-way bank alias (free)
  __shared__ unsigned short a_s[64 * 40];
  __shared__ unsigned short b_s[64 * 40];
  const int t = threadIdx.x;
  const int lane = t & 63, wid = t >> 6;
  const int wm = (wid & 1) * 32, wn = (wid >> 1) * 32;
  const int l16 = lane & 15, q = lane >> 4;
  f32x4 acc[2][2];
#pragma unroll
  for (int i = 0; i < 2; ++i)
#pragma unroll
    for (int j = 0; j < 2; ++j) acc[i][j] = (f32x4){0.f, 0.f, 0.f, 0.f};
  const unsigned short* Arow = A + (size_t)tileM * KDIM;
  const unsigned short* Brow = Bt + ((size_t)e * N + tileN) * (size_t)KDIM;
  const int sRow = t >> 2, sCh = (t & 3) * 8;
  for (int k0 = 0; k0 < KDIM; k0 += 32) {
    *(uint4*)&a_s[sRow * 40 + sCh] = *(const uint4*)&Arow[(size_t)sRow * KDIM + k0 + sCh];
    *(uint4*)&b_s[sRow * 40 + sCh] = *(const uint4*)&Brow[(size_t)sRow * KDIM + k0 + sCh];
    __syncthreads();
    short8 a0 = *(const short8*)&a_s[(wm + l16) * 40 + q * 8];
    short8 a1 = *(const short8*)&a_s[(wm + 16 + l16) * 40 + q * 8];
    short8 b0 = *(const short8*)&b_s[(wn + l16) * 40 + q * 8];
    short8 b1 = *(const short8*)&b_s[(wn + 16 + l16) * 40 + q * 8];
    acc[0][0] = __builtin_amdgcn_mfma_f32_16x16x32_bf16(a0, b0, acc[0][0], 0, 0, 0);
    acc[0][1] = __builtin_amdgcn_mfma_f32_16x16x32_bf16(a0, b1, acc[0][1], 0, 0, 0);
    acc[1][0] = __builtin_amdgcn_mfma_f32_16x16x32_bf16(a1, b0, acc[1][0], 0, 0, 0);
    acc[1][1] = __builtin_amdgcn_mfma_f32_16x16x32_bf16(a1, b1, acc[1][1], 0, 0, 0);
    __syncthreads();
  }
#pragma unroll
  for (int i = 0; i < 2; ++i)
#pragma unroll
    for (int j = 0; j < 2; ++j)
#pragma unroll
      for (int r = 0; r < 4; ++r) {
        const int gRow = tileM + wm + i * 16 + q * 4 + r;  // D row = quad*4+reg
        const int gCol = tileN + wn + j * 16 + l16;        // D col = lane&15
        float val = acc[i][j][r] + bias[e * N + gCol];
        if (EPI == 0) {
          Cout[(size_t)gRow * N + gCol] = f2bf(fmaxf(val, 0.f));
        } else {
          int s = entry[gRow];
          if (s >= 0) atomicAdd(&dOut[(size_t)(s >> 1) * N + gCol], val * topw[s]);
        }
      }
}

// ---------------- load-balance loss --------------------------------------
__global__ void loss_kernel(const float* __restrict__ usage, float* __restrict__ out) {
  if (threadIdx.x == 0) {
    float l = 0.f;
    for (int e = 0; e < NEXP; ++e) {
      float d = usage[e] * (1.f / B_ROWS) - 1.f / NEXP;
      l += d * d;
    }
    out[(size_t)B_ROWS * DOUT_N] = l * (1.f / NEXP);
  }
}

extern "C" void kernel_launch(void* const* d_in, const int* in_sizes, int n_in,
                              void* d_out, int out_size, void* d_ws, size_t ws_size,
                              hipStream_t stream) {
  (void)in_sizes; (void)n_in; (void)ws_size;
  const float* x   = (const float*)d_in[0];
  const float* W1  = (const float*)d_in[1];
  const float* b1  = (const float*)d_in[2];
  const float* W2  = (const float*)d_in[3];
  const float* b2  = (const float*)d_in[4];
  const float* W3  = (const float*)d_in[5];
  const float* b3  = (const float*)d_in[6];
  const float* Wg1 = (const float*)d_in[7];
  const float* bg1 = (const float*)d_in[8];
  const float* Wg2 = (const float*)d_in[9];
  const float* bg2 = (const float*)d_in[10];
  float* out = (float*)d_out;

  char* ws = (char*)d_ws;
  size_t p = 0;
  auto alloc = [&](size_t bytes) {
    void* r = ws + p;
    p = (p + bytes + 255) & ~(size_t)255;
    return r;
  };
  int*   off    = (int*)alloc(9 * 4);
  int*   counts = (int*)alloc(NEXP * 4);
  int*   fill   = (int*)alloc(NEXP * 4);
  float* usage  = (float*)alloc(NEXP * 4);
  int*   tidx   = (int*)alloc((size_t)B_ROWS * 2 * 4);
  float* tw     = (float*)alloc((size_t)B_ROWS * 2 * 4);
  int*   entry  = (int*)alloc((size_t)PAD_ROWS * 4);
  float* g      = (float*)alloc((size_t)B_ROWS * 512 * 4);
  unsigned short* Xg  = (unsigned short*)alloc((size_t)PAD_ROWS * DDIM * 2);
  unsigned short* W1t = (unsigned short*)alloc((size_t)NEXP * HDIM * DDIM * 2);
  unsigned short* W2t = (unsigned short*)alloc((size_t)NEXP * H2DIM * HDIM * 2);
  unsigned short* W3t = (unsigned short*)alloc((size_t)NEXP * DOUT_N * H2DIM * 2);
  unsigned short* h1  = (unsigned short*)alloc((size_t)PAD_ROWS * HDIM * 2);
  unsigned short* h2  = (unsigned short*)alloc((size_t)PAD_ROWS * H2DIM * 2);
  // total ws use: ~494 MB

  hipMemsetAsync(d_out, 0, (size_t)out_size * 4, stream);
  hipMemsetAsync(counts, 0, NEXP * 4, stream);
  hipMemsetAsync(fill, 0, NEXP * 4, stream);
  hipMemsetAsync(usage, 0, NEXP * 4, stream);
  hipMemsetAsync(entry, 0xFF, (size_t)PAD_ROWS * 4, stream);

  // weight transpose+convert (independent of routing)
  transpose_kernel<<<dim3(HDIM / 64, DDIM / 64, NEXP), 256, 0, stream>>>(W1, W1t, DDIM, HDIM);
  transpose_kernel<<<dim3(H2DIM / 64, HDIM / 64, NEXP), 256, 0, stream>>>(W2, W2t, HDIM, H2DIM);
  transpose_kernel<<<dim3(DOUT_N / 64, H2DIM / 64, NEXP), 256, 0, stream>>>(W3, W3t, H2DIM, DOUT_N);

  // gate (fp32 exact) + routing
  gate1_kernel<<<dim3(512 / 64, B_ROWS / 64), 256, 0, stream>>>(x, Wg1, bg1, g);
  gate2_kernel<<<B_ROWS / 4, 256, 0, stream>>>(g, Wg2, bg2, tidx, tw, counts, usage);
  offsets_kernel<<<1, 64, 0, stream>>>(counts, off);
  scatter_kernel<<<B_ROWS / 256, 256, 0, stream>>>(tidx, off, fill, entry);
  gather_kernel<<<PAD_ROWS, 256, 0, stream>>>(x, entry, Xg);

  // routed expert MLP (bf16 MFMA)
  expert_gemm<DDIM, 0><<<dim3(HDIM / 64, ROW_TILES), 256, 0, stream>>>(
      Xg, W1t, b1, h1, nullptr, tw, entry, off, HDIM);
  expert_gemm<HDIM, 0><<<dim3(H2DIM / 64, ROW_TILES), 256, 0, stream>>>(
      h1, W2t, b2, h2, nullptr, tw, entry, off, H2DIM);
  expert_gemm<H2DIM, 1><<<dim3(DOUT_N / 64, ROW_TILES), 256, 0, stream>>>(
      h2, W3t, b3, nullptr, out, tw, entry, off, DOUT_N);

  loss_kernel<<<1, 64, 0, stream>>>(usage, out);
}

// Round 2
// 1494.249 us; speedup vs baseline: 1.3002x; 1.3002x over previous
//
#include <hip/hip_runtime.h>

#define B_ROWS 8192
#define DDIM 1024
#define HDIM 4096
#define H2DIM 2048
#define DOUT_N 1024
#define NEXP 8
#define ROW_TILES 136            // ceil((2*8192 + 8*127)/128) = 136 tiles worst case
#define PAD_ROWS (ROW_TILES*128) // 17408

typedef __attribute__((ext_vector_type(8))) short short8;
typedef __attribute__((ext_vector_type(4))) float f32x4;

// RNE fp32 -> bf16 (finite inputs only)
__device__ inline unsigned short f2bf(float f) {
  unsigned int u = __builtin_bit_cast(unsigned int, f);
  u += 0x7fffu + ((u >> 16) & 1u);
  return (unsigned short)(u >> 16);
}

// async global->LDS, 16B per lane; lds base must be wave-uniform
__device__ inline void gld_lds16(const void* g, void* l) {
  __builtin_amdgcn_global_load_lds(
      (const __attribute__((address_space(1))) void*)g,
      (__attribute__((address_space(3))) void*)l, 16, 0, 0);
}

// ---------------- gate layer 1: g = relu(x @ Wg1 + bg1), fp32 ----------------
// [8192,1024] @ [1024,512]; 128x64 tile, 256 thr, 8x4/thread, K-step 16
__global__ __launch_bounds__(256) void gate1_kernel(
    const float* __restrict__ x, const float* __restrict__ Wg1,
    const float* __restrict__ bg1, float* __restrict__ g) {
  __shared__ float a_s[16][132];  // [k][row], +4 pad vs 128 to break store conflicts
  __shared__ float b_s[16][64];   // [k][col]
  const int t = threadIdx.x;
  const int row0 = blockIdx.y * 128;
  const int n0 = blockIdx.x * 64;
  const int tx = t & 15, ty = t >> 4;   // cols tx*4, rows ty*8
  float c[8][4] = {};
  const int la_row = t >> 2, la_kq = (t & 3) * 4;  // A-load: 2 iters cover 128 rows
  const int lb_kk = t >> 4, lb_c = (t & 15) * 4;   // B-load: 1 float4/thread
  for (int k0 = 0; k0 < DDIM; k0 += 16) {
#pragma unroll
    for (int i = 0; i < 2; ++i) {
      int row = la_row + i * 64;
      float4 av = *(const float4*)&x[(size_t)(row0 + row) * DDIM + k0 + la_kq];
      a_s[la_kq + 0][row] = av.x; a_s[la_kq + 1][row] = av.y;
      a_s[la_kq + 2][row] = av.z; a_s[la_kq + 3][row] = av.w;
    }
    *(float4*)&b_s[lb_kk][lb_c] = *(const float4*)&Wg1[(size_t)(k0 + lb_kk) * 512 + n0 + lb_c];
    __syncthreads();
#pragma unroll
    for (int kk = 0; kk < 16; ++kk) {
      float4 b4 = *(const float4*)&b_s[kk][tx * 4];
      float4 a4lo = *(const float4*)&a_s[kk][ty * 8];
      float4 a4hi = *(const float4*)&a_s[kk][ty * 8 + 4];
      float aa[8] = {a4lo.x, a4lo.y, a4lo.z, a4lo.w, a4hi.x, a4hi.y, a4hi.z, a4hi.w};
      float bb[4] = {b4.x, b4.y, b4.z, b4.w};
#pragma unroll
      for (int i = 0; i < 8; ++i)
#pragma unroll
        for (int j = 0; j < 4; ++j) c[i][j] += aa[i] * bb[j];
    }
    __syncthreads();
  }
  float bb[4];
#pragma unroll
  for (int j = 0; j < 4; ++j) bb[j] = bg1[n0 + tx * 4 + j];
#pragma unroll
  for (int i = 0; i < 8; ++i) {
    float4 v;
    v.x = fmaxf(c[i][0] + bb[0], 0.f);
    v.y = fmaxf(c[i][1] + bb[1], 0.f);
    v.z = fmaxf(c[i][2] + bb[2], 0.f);
    v.w = fmaxf(c[i][3] + bb[3], 0.f);
    *(float4*)&g[(size_t)(row0 + ty * 8 + i) * 512 + n0 + tx * 4] = v;
  }
}

// ------ gate layer 2 + softmax + top2 + renorm + usage/count accumulation ----
// one wave per row; fp32 exact path to keep routing identical to numpy ref
__global__ __launch_bounds__(256) void gate2_kernel(
    const float* __restrict__ g, const float* __restrict__ Wg2,
    const float* __restrict__ bg2, int* __restrict__ top_idx,
    float* __restrict__ top_w, int* __restrict__ counts,
    float* __restrict__ usage) {
  __shared__ float w2t[NEXP * 512];  // transposed [e][k]
  __shared__ float us[NEXP];
  __shared__ int cs[NEXP];
  const int t = threadIdx.x;
  for (int i = t; i < NEXP * 512; i += 256) {
    int k = i >> 3, e = i & 7;
    w2t[e * 512 + k] = Wg2[i];
  }
  if (t < NEXP) { us[t] = 0.f; cs[t] = 0; }
  __syncthreads();
  const int lane = t & 63, wid = t >> 6;
  const int row = blockIdx.x * 4 + wid;
  float part[NEXP] = {};
  const float* grow = &g[(size_t)row * 512];
#pragma unroll
  for (int j = 0; j < 8; ++j) {
    int k = lane + j * 64;
    float gv = grow[k];
#pragma unroll
    for (int e = 0; e < NEXP; ++e) part[e] += gv * w2t[e * 512 + k];
  }
#pragma unroll
  for (int e = 0; e < NEXP; ++e)
    for (int m = 32; m >= 1; m >>= 1) part[e] += __shfl_xor(part[e], m);
  if (lane == 0) {
    float p[NEXP];
    float mx = -1e30f;
#pragma unroll
    for (int e = 0; e < NEXP; ++e) { p[e] = part[e] + bg2[e]; mx = fmaxf(mx, p[e]); }
    float s = 0.f;
#pragma unroll
    for (int e = 0; e < NEXP; ++e) { p[e] = expf(p[e] - mx); s += p[e]; }
    float inv = 1.f / s;
#pragma unroll
    for (int e = 0; e < NEXP; ++e) { p[e] *= inv; atomicAdd(&us[e], p[e]); }
    int i0 = 0; float b0 = p[0];
    for (int e = 1; e < NEXP; ++e) if (p[e] > b0) { b0 = p[e]; i0 = e; }
    int i1 = -1; float b1 = -1.f;
    for (int e = 0; e < NEXP; ++e) {
      if (e == i0) continue;
      if (p[e] > b1) { b1 = p[e]; i1 = e; }
    }
    float e1 = expf(b1 - b0);          // renorm = softmax over the 2 top probs
    float w0 = 1.f / (1.f + e1);
    top_idx[row * 2 + 0] = i0; top_idx[row * 2 + 1] = i1;
    top_w[row * 2 + 0] = w0;   top_w[row * 2 + 1] = e1 * w0;
    atomicAdd(&cs[i0], 1); atomicAdd(&cs[i1], 1);
  }
  __syncthreads();
  if (t < NEXP) { atomicAdd(&usage[t], us[t]); atomicAdd(&counts[t], cs[t]); }
}

// --------- offsets: 128-aligned segment starts per expert (single thread) ----
__global__ void offsets_kernel(const int* __restrict__ counts, int* __restrict__ off) {
  if (threadIdx.x == 0) {
    int acc = 0;
    off[0] = 0;
    for (int e = 0; e < NEXP; ++e) {
      acc += (counts[e] + 127) & ~127;
      off[e + 1] = acc;
    }
  }
}

// --------- scatter rows into per-expert entry lists (entry = row*2+k) --------
__global__ __launch_bounds__(256) void scatter_kernel(
    const int* __restrict__ top_idx, const int* __restrict__ off,
    int* __restrict__ fill, int* __restrict__ entry) {
  int row = blockIdx.x * 256 + threadIdx.x;
#pragma unroll
  for (int k = 0; k < 2; ++k) {
    int e = top_idx[row * 2 + k];
    int pos = atomicAdd(&fill[e], 1);
    entry[off[e] + pos] = row * 2 + k;
  }
}

// --------- gather x rows (fp32) -> dense bf16 A matrix by entry position -----
__global__ __launch_bounds__(256) void gather_kernel(
    const float* __restrict__ x, const int* __restrict__ entry,
    unsigned short* __restrict__ Xg) {
  const int r = blockIdx.x;
  const int s = entry[r];
  const int t = threadIdx.x;
  unsigned long long packed = 0ull;
  if (s >= 0) {
    float4 f = *(const float4*)&x[(size_t)(s >> 1) * DDIM + t * 4];
    packed = (unsigned long long)f2bf(f.x) |
             ((unsigned long long)f2bf(f.y) << 16) |
             ((unsigned long long)f2bf(f.z) << 32) |
             ((unsigned long long)f2bf(f.w) << 48);
  }
  *(unsigned long long*)&Xg[(size_t)r * DDIM + t * 4] = packed;
}

// --------- weight transpose+convert: [K][N] fp32 -> [N][K] bf16 per expert ---
__global__ __launch_bounds__(256) void transpose_kernel(
    const float* __restrict__ src, unsigned short* __restrict__ dst,
    int K, int N) {
  __shared__ float tile[64][65];
  const size_t eoff = (size_t)blockIdx.z * K * N;
  const int k0 = blockIdx.y * 64, n0 = blockIdx.x * 64;
  const int t = threadIdx.x;
#pragma unroll
  for (int i = 0; i < 16; ++i) {
    int idx = t + i * 256;
    int kk = idx >> 6, nn = idx & 63;
    tile[kk][nn] = src[eoff + (size_t)(k0 + kk) * N + n0 + nn];
  }
  __syncthreads();
#pragma unroll
  for (int i = 0; i < 16; ++i) {
    int idx = t + i * 256;
    int nn = idx >> 6, kk = idx & 63;
    dst[eoff + (size_t)(n0 + nn) * K + k0 + kk] = f2bf(tile[kk][nn]);
  }
}

// ---------------- expert GEMM: m97 structure, 128x128 tile per block ---------
// A: [PAD_ROWS][KDIM] bf16 dense by entry pos; Bt: [E][N][KDIM] bf16
// 4 waves, each owns 64x64 (4x4 frags of 16x16x32); BK=32;
// global_load_lds width=16, unpadded [128][32] LDS (wave-uniform base + lane*16)
// EPI 0: relu(acc+bias) -> bf16 Cout ; EPI 1: atomicAdd(out, w*(acc+bias))
template <int KDIM, int EPI>
__global__ __launch_bounds__(256) void expert_gemm(
    const unsigned short* __restrict__ A, const unsigned short* __restrict__ Bt,
    const float* __restrict__ bias, unsigned short* __restrict__ Cout,
    float* __restrict__ dOut, const float* __restrict__ topw,
    const int* __restrict__ entry, const int* __restrict__ off, int N) {
  const int tileM = blockIdx.y * 128;
  if (tileM >= off[NEXP]) return;  // beyond padded total: uniform exit
  int e = 0;
  while (e < NEXP - 1 && off[e + 1] <= tileM) ++e;
  const int tileN = blockIdx.x * 128;
  __shared__ unsigned short a_s[128 * 32];  // [row][k], unpadded (global_load_lds)
  __shared__ unsigned short b_s[128 * 32];
  const int t = threadIdx.x;
  const int lane = t & 63, wid = t >> 6;
  const int wr = (wid & 1) * 64, wc = (wid >> 1) * 64;
  const int l16 = lane & 15, q = lane >> 4;
  f32x4 acc[4][4];
#pragma unroll
  for (int i = 0; i < 4; ++i)
#pragma unroll
    for (int j = 0; j < 4; ++j) acc[i][j] = (f32x4){0.f, 0.f, 0.f, 0.f};
  const unsigned short* Abase = A + (size_t)tileM * KDIM;
  const unsigned short* Bbase = Bt + ((size_t)e * N + tileN) * (size_t)KDIM;
  const int srow = 32 * wid;       // this wave stages rows [srow, srow+32)
  const int lrow = lane >> 2;      // 0..15 within 16-row group
  const int lch = (lane & 3) * 8;  // element offset (8 bf16 = 16B)
  for (int k0 = 0; k0 < KDIM; k0 += 32) {
#pragma unroll
    for (int j = 0; j < 2; ++j) {
      const int r0 = srow + 16 * j;
      gld_lds16(Abase + (size_t)(r0 + lrow) * KDIM + k0 + lch, &a_s[r0 * 32]);
      gld_lds16(Bbase + (size_t)(r0 + lrow) * KDIM + k0 + lch, &b_s[r0 * 32]);
    }
    __syncthreads();
    short8 af[4], bf[4];
#pragma unroll
    for (int i = 0; i < 4; ++i) {
      af[i] = *(const short8*)&a_s[(wr + 16 * i + l16) * 32 + q * 8];
      bf[i] = *(const short8*)&b_s[(wc + 16 * i + l16) * 32 + q * 8];
    }
#pragma unroll
    for (int i = 0; i < 4; ++i)
#pragma unroll
      for (int j = 0; j < 4; ++j)
        acc[i][j] = __builtin_amdgcn_mfma_f32_16x16x32_bf16(af[i], bf[j], acc[i][j], 0, 0, 0);
    __syncthreads();
  }
  if (EPI == 0) {
#pragma unroll
    for (int j = 0; j < 4; ++j) {
      const int gCol = tileN + wc + 16 * j + l16;
      const float bcol = bias[e * N + gCol];
#pragma unroll
      for (int i = 0; i < 4; ++i)
#pragma unroll
        for (int r = 0; r < 4; ++r) {
          const int gRow = tileM + wr + 16 * i + q * 4 + r;  // D row = quad*4+reg
          Cout[(size_t)gRow * N + gCol] = f2bf(fmaxf(acc[i][j][r] + bcol, 0.f));
        }
    }
  } else {
    float bcol[4];
#pragma unroll
    for (int j = 0; j < 4; ++j) bcol[j] = bias[e * N + tileN + wc + 16 * j + l16];
#pragma unroll
    for (int i = 0; i < 4; ++i)
#pragma unroll
      for (int r = 0; r < 4; ++r) {
        const int gRow = tileM + wr + 16 * i + q * 4 + r;
        const int s = entry[gRow];
        if (s < 0) continue;
        const float w = topw[s];
        float* orow = dOut + (size_t)(s >> 1) * N;
#pragma unroll
        for (int j = 0; j < 4; ++j) {
          const int gCol = tileN + wc + 16 * j + l16;
          atomicAdd(&orow[gCol], (acc[i][j][r] + bcol[j]) * w);
        }
      }
  }
}

// ---------------- load-balance loss --------------------------------------
__global__ void loss_kernel(const float* __restrict__ usage, float* __restrict__ out) {
  if (threadIdx.x == 0) {
    float l = 0.f;
    for (int e = 0; e < NEXP; ++e) {
      float d = usage[e] * (1.f / B_ROWS) - 1.f / NEXP;
      l += d * d;
    }
    out[(size_t)B_ROWS * DOUT_N] = l * (1.f / NEXP);
  }
}

extern "C" void kernel_launch(void* const* d_in, const int* in_sizes, int n_in,
                              void* d_out, int out_size, void* d_ws, size_t ws_size,
                              hipStream_t stream) {
  (void)in_sizes; (void)n_in; (void)ws_size;
  const float* x   = (const float*)d_in[0];
  const float* W1  = (const float*)d_in[1];
  const float* b1  = (const float*)d_in[2];
  const float* W2  = (const float*)d_in[3];
  const float* b2  = (const float*)d_in[4];
  const float* W3  = (const float*)d_in[5];
  const float* b3  = (const float*)d_in[6];
  const float* Wg1 = (const float*)d_in[7];
  const float* bg1 = (const float*)d_in[8];
  const float* Wg2 = (const float*)d_in[9];
  const float* bg2 = (const float*)d_in[10];
  float* out = (float*)d_out;

  char* ws = (char*)d_ws;
  size_t p = 0;
  auto alloc = [&](size_t bytes) {
    void* r = ws + p;
    p = (p + bytes + 255) & ~(size_t)255;
    return r;
  };
  int*   off    = (int*)alloc(9 * 4);
  int*   counts = (int*)alloc(NEXP * 4);
  int*   fill   = (int*)alloc(NEXP * 4);
  float* usage  = (float*)alloc(NEXP * 4);
  int*   tidx   = (int*)alloc((size_t)B_ROWS * 2 * 4);
  float* tw     = (float*)alloc((size_t)B_ROWS * 2 * 4);
  int*   entry  = (int*)alloc((size_t)PAD_ROWS * 4);
  float* g      = (float*)alloc((size_t)B_ROWS * 512 * 4);
  unsigned short* Xg  = (unsigned short*)alloc((size_t)PAD_ROWS * DDIM * 2);
  unsigned short* W1t = (unsigned short*)alloc((size_t)NEXP * HDIM * DDIM * 2);
  unsigned short* W2t = (unsigned short*)alloc((size_t)NEXP * H2DIM * HDIM * 2);
  unsigned short* W3t = (unsigned short*)alloc((size_t)NEXP * DOUT_N * H2DIM * 2);
  unsigned short* h1  = (unsigned short*)alloc((size_t)PAD_ROWS * HDIM * 2);
  unsigned short* h2  = (unsigned short*)alloc((size_t)PAD_ROWS * H2DIM * 2);
  // total ws use: ~501 MB

  hipMemsetAsync(d_out, 0, (size_t)out_size * 4, stream);
  hipMemsetAsync(counts, 0, NEXP * 4, stream);
  hipMemsetAsync(fill, 0, NEXP * 4, stream);
  hipMemsetAsync(usage, 0, NEXP * 4, stream);
  hipMemsetAsync(entry, 0xFF, (size_t)PAD_ROWS * 4, stream);

  // weight transpose+convert (independent of routing)
  transpose_kernel<<<dim3(HDIM / 64, DDIM / 64, NEXP), 256, 0, stream>>>(W1, W1t, DDIM, HDIM);
  transpose_kernel<<<dim3(H2DIM / 64, HDIM / 64, NEXP), 256, 0, stream>>>(W2, W2t, HDIM, H2DIM);
  transpose_kernel<<<dim3(DOUT_N / 64, H2DIM / 64, NEXP), 256, 0, stream>>>(W3, W3t, H2DIM, DOUT_N);

  // gate (fp32 exact) + routing
  gate1_kernel<<<dim3(512 / 64, B_ROWS / 128), 256, 0, stream>>>(x, Wg1, bg1, g);
  gate2_kernel<<<B_ROWS / 4, 256, 0, stream>>>(g, Wg2, bg2, tidx, tw, counts, usage);
  offsets_kernel<<<1, 64, 0, stream>>>(counts, off);
  scatter_kernel<<<B_ROWS / 256, 256, 0, stream>>>(tidx, off, fill, entry);
  gather_kernel<<<PAD_ROWS, 256, 0, stream>>>(x, entry, Xg);

  // routed expert MLP (bf16 MFMA, m97 structure)
  expert_gemm<DDIM, 0><<<dim3(HDIM / 128, ROW_TILES), 256, 0, stream>>>(
      Xg, W1t, b1, h1, nullptr, tw, entry, off, HDIM);
  expert_gemm<HDIM, 0><<<dim3(H2DIM / 128, ROW_TILES), 256, 0, stream>>>(
      h1, W2t, b2, h2, nullptr, tw, entry, off, H2DIM);
  expert_gemm<H2DIM, 1><<<dim3(DOUT_N / 128, ROW_TILES), 256, 0, stream>>>(
      h2, W3t, b3, nullptr, out, tw, entry, off, DOUT_N);

  loss_kernel<<<1, 64, 0, stream>>>(usage, out);
}